// Round 6
// baseline (145.798 us; speedup 1.0000x reference)
//
#include <hip/hip_runtime.h>
#include <stdint.h>

// B=2, H=16, L=2048, D=64 causal attention, fp32 in/out.
#define B_ 2
#define H_ 16
#define L_ 2048
#define D_ 64
#define BN 64   // KV rows per tile; also q rows per strip

typedef __attribute__((ext_vector_type(8))) _Float16 half8;
typedef __attribute__((ext_vector_type(4))) _Float16 half4;
typedef __attribute__((ext_vector_type(4))) float    f32x4;

// ROUND-6: one 256-thread block owns FOUR strips {k, 31-k, 15-k, 16+k}
// (k = 0..7); each wave holds 16 q-rows of EACH strip (64 q/wave).
// Grid = 8 x 32bh = 256 blocks = exactly 1 block/CU.
//
// WHY (r1/r2/r4/r5 post-mortems): 2, 4, or desynced waves/SIMD all cost
// ~2000 cyc/wave-unit -> the limiter is per-CU serialized work, not TLP.
// kf/bv LDS fragments are q-INDEPENDENT, so 64 q/wave amortizes all LDS
// reads (-32%/unit) and all staging (global issue + cvt + ds_write,
// -44%/unit). Work per block = 66 units for every k -> uniform, no tail.
// 1 wave/SIMD: latency hidden by 4 independent unit-chains per iteration
// (ILP instead of the TLP that r4 proved useless).
//
// Raw barrier (T4-lite): lgkmcnt(0)+s_barrier via asm, NOT __syncthreads
// (which drains vmcnt(0) and exposes the fresh prefetch's full latency).
// Hazards: stage(t+1) writes buf^1, whose last readers (compute t-1)
// drained their ds_reads at the previous lgkmcnt(0)+barrier; stage's
// register inputs come from the prefetch issued one full iteration ago
// (compiler inserts the counted vmcnt); prefetch(t+2)'s loads legally
// stay in flight across the barrier.
//
// __launch_bounds__ 2nd arg is MIN BLOCKS PER CU on this hipcc (r3
// post-mortem); (256,1) -> VGPR cap 512, no spill risk (~220 live).
//
// blockIdx decode (assumes round-robin i%8 -> XCD): bh = ((i>>3)&3)*8+(i&7)
// gives each XCD 4 fixed bh's (4 MB K+V) -> K/V stream L2-local.

#define BARRIER() do {                                        \
    __builtin_amdgcn_sched_barrier(0);                        \
    asm volatile("s_waitcnt lgkmcnt(0)" ::: "memory");        \
    __builtin_amdgcn_s_barrier();                             \
    __builtin_amdgcn_sched_barrier(0);                        \
} while (0)

__global__ __launch_bounds__(256, 1) void fa_fwd(
    const float* __restrict__ Q, const float* __restrict__ K,
    const float* __restrict__ V, float* __restrict__ O)
{
    const int i  = blockIdx.x;
    const int bh = ((i >> 3) & 3) * 8 + (i & 7);
    const int k  = i >> 5;               // 0..7 strip-group
    // Strips: pair1 = (k, 31-k), pair2 = (15-k, 16+k).
    const int d1Y = k;                   // pair1 short strip
    const int d1X = 31 - k;              // pair1 long strip == maxT
    const int d2Y = 15 - k;              // pair2 short strip
    const int d2X = 16 + k;              // pair2 long strip
    const int maxT = d1X;

    const int tid  = threadIdx.x;
    const int wrow = tid >> 6;           // wave = 16-row band within each strip
    const int lane = tid & 63;
    const int l16  = lane & 15;
    const int quad = lane >> 4;

    const size_t base = (size_t)bh * (size_t)(L_ * D_);
    const float* Qb = Q + base;
    const float* Kb = K + base;
    const float* Vb = V + base;
    float*       Ob = O + base;

    // Double-buffered shared tiles (34,816 B; 1 block/CU).
    __shared__ __align__(16) _Float16 Klds [2][BN][72];  // row-major K
    __shared__ __align__(16) _Float16 Vtlds[2][D_][64];  // V^T, 8B-block swizzled

    // ---- staging: every thread stages a K quarter AND a V quarter ----
    const int srow  = tid >> 4;          // K: row 0..15 (x4)
    const int scol  = (tid & 15) * 4;    // K: col
    const int vw    = wrow;              // V: 16-row band 0..3
    const int vlane = lane;              // V: d = vlane

    float fk[16];  // K prefetch regs (float4[4])
    float fv[16];  // V prefetch regs (16 scalars)

    auto prefetch = [&](int kv0) {
        float4* kq = (float4*)fk;
        const float* kp = Kb + (size_t)kv0 * D_ + (size_t)tid * 4;
        #pragma unroll
        for (int u = 0; u < 4; ++u) kq[u] = *(const float4*)(kp + u * 1024);
        const float* vp = Vb + (size_t)(kv0 + vw * 16) * D_ + vlane;
        #pragma unroll
        for (int rr = 0; rr < 16; ++rr) fv[rr] = vp[rr * D_];
    };

    auto stage = [&](int buf) {
        const float4* kq = (const float4*)fk;
        #pragma unroll
        for (int u = 0; u < 4; ++u) {
            half4 ks;
            ks[0] = (_Float16)kq[u].x; ks[1] = (_Float16)kq[u].y;
            ks[2] = (_Float16)kq[u].z; ks[3] = (_Float16)kq[u].w;
            *(half4*)&Klds[buf][u * 16 + srow][scol] = ks;
        }
        #pragma unroll
        for (int c = 0; c < 4; ++c) {
            half4 vs;
            vs[0] = (_Float16)fv[4 * c + 0]; vs[1] = (_Float16)fv[4 * c + 1];
            vs[2] = (_Float16)fv[4 * c + 2]; vs[3] = (_Float16)fv[4 * c + 3];
            // kv>>2 = 4*vw + c; pos = (kv>>2 + d + 4*(d>>4)) & 15, d = vlane
            const int pp = ((4 * vw + c) + vlane + 4 * (vlane >> 4)) & 15;
            *(half4*)((char*)&Vtlds[buf][vlane][0] + pp * 8) = vs;
        }
    };

    // ---- per-strip state (4 strips) ----
    const float cs = 0.18033688011112042f; // (1/8) * log2(e), folded into Q
    const int q1Y_abs = d1Y * 64 + wrow * 16 + l16;
    const int q1X_abs = d1X * 64 + wrow * 16 + l16;
    const int q2Y_abs = d2Y * 64 + wrow * 16 + l16;
    const int q2X_abs = d2X * 64 + wrow * 16 + l16;
    half8 qf1Y[2], qf1X[2], qf2Y[2], qf2X[2];
    auto loadQ = [&](half8* qf, int q_abs) {
        #pragma unroll
        for (int c = 0; c < 2; ++c) {
            const float* pq = Qb + (size_t)q_abs * D_ + c * 32 + quad * 8;
            float4 a = *(const float4*)(pq);
            float4 b = *(const float4*)(pq + 4);
            half8 f;
            f[0] = (_Float16)(a.x * cs); f[1] = (_Float16)(a.y * cs);
            f[2] = (_Float16)(a.z * cs); f[3] = (_Float16)(a.w * cs);
            f[4] = (_Float16)(b.x * cs); f[5] = (_Float16)(b.y * cs);
            f[6] = (_Float16)(b.z * cs); f[7] = (_Float16)(b.w * cs);
            qf[c] = f;
        }
    };
    loadQ(qf1Y, q1Y_abs); loadQ(qf1X, q1X_abs);
    loadQ(qf2Y, q2Y_abs); loadQ(qf2X, q2X_abs);

    f32x4 o1Y[4], o1X[4], o2Y[4], o2X[4];
    #pragma unroll
    for (int n = 0; n < 4; ++n) {
        o1Y[n] = (f32x4){0.f,0.f,0.f,0.f}; o1X[n] = (f32x4){0.f,0.f,0.f,0.f};
        o2Y[n] = (f32x4){0.f,0.f,0.f,0.f}; o2X[n] = (f32x4){0.f,0.f,0.f,0.f};
    }
    f32x4 lsq1Y = (f32x4){0.f,0.f,0.f,0.f}, lsq1X = (f32x4){0.f,0.f,0.f,0.f};
    f32x4 lsq2Y = (f32x4){0.f,0.f,0.f,0.f}, lsq2X = (f32x4){0.f,0.f,0.f,0.f};
    half4 one4;
    one4[0] = (_Float16)1.f; one4[1] = (_Float16)1.f;
    one4[2] = (_Float16)1.f; one4[3] = (_Float16)1.f;

    // One pair (X = long strip, active whenever called; Y = short, if aY).
    // Shares kf/bv LDS reads between the two strips.
    auto doPair = [&](bool aY, int t, int buf, int dX, int dY,
                      int qXa, int qYa,
                      const half8* qfX, const half8* qfY,
                      f32x4* oX, f32x4* oY, f32x4& lsqX, f32x4& lsqY) {
        const int kv0 = t * BN;
        f32x4 sX[4], sY[4];
        #pragma unroll
        for (int n = 0; n < 4; ++n) {
            f32x4 aXv = (f32x4){0.f,0.f,0.f,0.f};
            f32x4 aYv = (f32x4){0.f,0.f,0.f,0.f};
            #pragma unroll
            for (int c = 0; c < 2; ++c) {
                half8 kf = *(const half8*)&Klds[buf][n * 16 + l16][c * 32 + quad * 8];
                aXv = __builtin_amdgcn_mfma_f32_16x16x32_f16(kf, qfX[c], aXv, 0, 0, 0);
                if (aY)
                    aYv = __builtin_amdgcn_mfma_f32_16x16x32_f16(kf, qfY[c], aYv, 0, 0, 0);
            }
            sX[n] = aXv; sY[n] = aYv;
        }
        if (t == dX) {                       // long-strip diagonal mask
            #pragma unroll
            for (int n = 0; n < 4; ++n) {
                const int kvr = kv0 + n * 16 + quad * 4;
                #pragma unroll
                for (int r = 0; r < 4; ++r)
                    if (kvr + r > qXa) sX[n][r] = -1e30f;
            }
        }
        if (aY && t == dY) {                 // short-strip diagonal mask
            #pragma unroll
            for (int n = 0; n < 4; ++n) {
                const int kvr = kv0 + n * 16 + quad * 4;
                #pragma unroll
                for (int r = 0; r < 4; ++r)
                    if (kvr + r > qYa) sY[n][r] = -1e30f;
            }
        }
        half4 phX[4], phY[4];
        if (aY) {
            #pragma unroll
            for (int n = 0; n < 4; ++n)
                #pragma unroll
                for (int r = 0; r < 4; ++r) {
                    phX[n][r] = (_Float16)__builtin_amdgcn_exp2f(sX[n][r]);
                    phY[n][r] = (_Float16)__builtin_amdgcn_exp2f(sY[n][r]);
                }
            #pragma unroll
            for (int nk = 0; nk < 4; ++nk) {
                lsqX = __builtin_amdgcn_mfma_f32_16x16x16f16(phX[nk], one4, lsqX, 0, 0, 0);
                lsqY = __builtin_amdgcn_mfma_f32_16x16x16f16(phY[nk], one4, lsqY, 0, 0, 0);
            }
            #pragma unroll
            for (int nt = 0; nt < 4; ++nt) {
                const char* row = (const char*)&Vtlds[buf][nt * 16 + l16][0];
                #pragma unroll
                for (int nk = 0; nk < 4; ++nk) {
                    const int pp = (4 * nk + quad + l16 + 4 * nt) & 15;
                    half4 bv = *(const half4*)(row + pp * 8);
                    oX[nt] = __builtin_amdgcn_mfma_f32_16x16x16f16(phX[nk], bv, oX[nt], 0, 0, 0);
                    oY[nt] = __builtin_amdgcn_mfma_f32_16x16x16f16(phY[nk], bv, oY[nt], 0, 0, 0);
                }
            }
        } else {
            #pragma unroll
            for (int n = 0; n < 4; ++n)
                #pragma unroll
                for (int r = 0; r < 4; ++r)
                    phX[n][r] = (_Float16)__builtin_amdgcn_exp2f(sX[n][r]);
            #pragma unroll
            for (int nk = 0; nk < 4; ++nk)
                lsqX = __builtin_amdgcn_mfma_f32_16x16x16f16(phX[nk], one4, lsqX, 0, 0, 0);
            #pragma unroll
            for (int nt = 0; nt < 4; ++nt) {
                const char* row = (const char*)&Vtlds[buf][nt * 16 + l16][0];
                #pragma unroll
                for (int nk = 0; nk < 4; ++nk) {
                    const int pp = (4 * nk + quad + l16 + 4 * nt) & 15;
                    half4 bv = *(const half4*)(row + pp * 8);
                    oX[nt] = __builtin_amdgcn_mfma_f32_16x16x16f16(phX[nk], bv, oX[nt], 0, 0, 0);
                }
            }
        }
    };

    // ---- pipeline prologue ----
    prefetch(0);
    stage(0);
    prefetch(BN);              // maxT >= 24, tile 1 always exists
    BARRIER();

    // ---- main loop: stage+prefetch first; raw barrier keeps loads in flight ----
    for (int t = 0; t <= maxT; ++t) {
        const int buf = t & 1;

        if (t < maxT)      stage(buf ^ 1);        // regs prefetched last iter
        if (t + 2 <= maxT) prefetch((t + 2) * BN);

        // pair 1: X = d1X (== maxT, always active), Y = d1Y
        doPair(t <= d1Y, t, buf, d1X, d1Y, q1X_abs, q1Y_abs,
               qf1X, qf1Y, o1X, o1Y, lsq1X, lsq1Y);
        // pair 2: X = d2X, Y = d2Y
        if (t <= d2X)
            doPair(t <= d2Y, t, buf, d2X, d2Y, q2X_abs, q2Y_abs,
                   qf2X, qf2Y, o2X, o2Y, lsq2X, lsq2Y);

        if (t < maxT) BARRIER();
    }

    // ---- epilogue (wave-private): normalize by MFMA row-sums, store ----
    auto epi = [&](const f32x4* o, f32x4 lsq, int d) {
        float linv[4];
        #pragma unroll
        for (int r = 0; r < 4; ++r) linv[r] = 1.0f / lsq[r];
        const int qr0 = d * 64 + wrow * 16 + quad * 4;
        #pragma unroll
        for (int nt = 0; nt < 4; ++nt)
            #pragma unroll
            for (int r = 0; r < 4; ++r)
                Ob[(size_t)(qr0 + r) * D_ + nt * 16 + l16] = o[nt][r] * linv[r];
    };
    epi(o1Y, lsq1Y, d1Y);
    epi(o1X, lsq1X, d1X);
    epi(o2Y, lsq2Y, d2Y);
    epi(o2X, lsq2X, d2X);
}

extern "C" void kernel_launch(void* const* d_in, const int* in_sizes, int n_in,
                              void* d_out, int out_size, void* d_ws, size_t ws_size,
                              hipStream_t stream) {
    const float* Q = (const float*)d_in[0];
    const float* K = (const float*)d_in[1];
    const float* V = (const float*)d_in[2];
    float*       O = (float*)d_out;
    fa_fwd<<<dim3(8 * B_ * H_), dim3(256), 0, stream>>>(Q, K, V, O);
}

// Round 7
// 142.008 us; speedup vs baseline: 1.0267x; 1.0267x over previous
//
#include <hip/hip_runtime.h>
#include <stdint.h>

// B=2, H=16, L=2048, D=64 causal attention, fp32 in/out.
#define B_ 2
#define H_ 16
#define L_ 2048
#define D_ 64
#define BN 64   // KV rows per tile; also q rows per strip

typedef __attribute__((ext_vector_type(8))) _Float16 half8;
typedef __attribute__((ext_vector_type(4))) _Float16 half4;
typedef __attribute__((ext_vector_type(4))) float    f32x4;

// ROUND-7: r5 config (the measured optimum of the TLP x q/wave tradeoff:
// 32q/wave, 2 waves/SIMD; r1=16qx4w:56us, r5=32qx2w:54us, r6=64qx1w:76us)
// plus a CROSS-TILE 2-STAGE PIPELINE to break the per-tile serial chain
// QK^T -> exp2 -> cvt -> PV that r6 proved is the exposed-latency culprit.
//
// Iteration t:  stage(t+1); prefetch(t+2);
//               QK^T(t)           (chain 1: MFMA, reads K[t&1])
//               PV(t-1)+lsq(t-1)  (chain 2: MFMA, reads V[(t-1)%3], consumes
//                                  ph held in regs across the barrier)
//               exp(t) -> ph      (TRANS, overlaps chain 2)
//               BARRIER (lgkmcnt(0)-only)
// Chains 1+2 are independent -> the scheduler interleaves them even in
// B-only mode (65% of tiles), instead of stalling at each stage boundary.
//
// V is TRIPLE-buffered: PV(t-1) reads V[(t-1)%3] while stage writes
// V[(t+1)%3] (indices differ by 2 mod 3 -> never alias). K stays double.
// LDS = 2*64*72*2 + 3*64*64*2 = 43,008 B -> 2 blocks/CU. Hazards under the
// raw lgkmcnt(0)+s_barrier: stage(t+1) overwrites K[(t+1)&1], whose readers
// QK^T(t-1) drained their ds_reads at the end-of-(t-1) lgkmcnt(0); same for
// V (readers PV(t-2) ran in iter t-1). Prefetch's global loads legally stay
// in flight across the barrier (no vmcnt(0) drain; compiler inserts the
// counted vmcnt before stage's register use).
//
// Kept from r5/r6: cs=(1/8)log2e folded into fp16 Q; row-sums via ones-MFMA
// (normalizer = sum of the same fp16 P used in PV); raw barrier.
// Dropped: tile-order rotation (r5: no perf delta, +25% FETCH).
//
// __launch_bounds__ 2nd arg is MIN BLOCKS PER CU on this hipcc (r3
// post-mortem: (512,4) capped VGPR at 64 and spilled to scratch).
//
// blockIdx decode (assumes round-robin i%8 -> XCD): bh = ((i>>3)&3)*8+(i&7)
// gives each XCD all 16 pairs of 4 fixed bh's -> K/V stream L2-local.

#define BARRIER() do {                                        \
    __builtin_amdgcn_sched_barrier(0);                        \
    asm volatile("s_waitcnt lgkmcnt(0)" ::: "memory");        \
    __builtin_amdgcn_s_barrier();                             \
    __builtin_amdgcn_sched_barrier(0);                        \
} while (0)

__global__ __launch_bounds__(256, 2) void fa_fwd(
    const float* __restrict__ Q, const float* __restrict__ K,
    const float* __restrict__ V, float* __restrict__ O)
{
    const int i  = blockIdx.x;
    const int bh = ((i >> 3) & 3) * 8 + (i & 7);
    const int p  = i >> 5;               // 0..15
    const int dY = p;                    // short strip diagonal
    const int dX = 31 - p;               // long strip diagonal (>= 16)

    const int tid  = threadIdx.x;
    const int wrow = tid >> 6;           // wave = 16-row band within each strip
    const int lane = tid & 63;
    const int l16  = lane & 15;
    const int quad = lane >> 4;

    const size_t base = (size_t)bh * (size_t)(L_ * D_);
    const float* Qb = Q + base;
    const float* Kb = K + base;
    const float* Vb = V + base;
    float*       Ob = O + base;

    // K double-buffered, V triple-buffered (43,008 B -> 2 blocks/CU).
    __shared__ __align__(16) _Float16 Klds [2][BN][72];  // row-major K
    __shared__ __align__(16) _Float16 Vtlds[3][D_][64];  // V^T, 8B-block swizzled

    // ---- staging: every thread stages a K quarter AND a V quarter ----
    const int srow  = tid >> 4;          // K: row 0..15 (x4)
    const int scol  = (tid & 15) * 4;    // K: col
    const int vw    = wrow;              // V: 16-row band 0..3
    const int vlane = lane;              // V: d = vlane

    float fk[16];  // K prefetch regs (float4[4])
    float fv[16];  // V prefetch regs (16 scalars)

    auto prefetch = [&](int kv0) {
        float4* kq = (float4*)fk;
        const float* kp = Kb + (size_t)kv0 * D_ + (size_t)tid * 4;
        #pragma unroll
        for (int u = 0; u < 4; ++u) kq[u] = *(const float4*)(kp + u * 1024);
        const float* vp = Vb + (size_t)(kv0 + vw * 16) * D_ + vlane;
        #pragma unroll
        for (int rr = 0; rr < 16; ++rr) fv[rr] = vp[rr * D_];
    };

    auto stage = [&](int t) {
        const int kb = t & 1, vb = t % 3;
        const float4* kq = (const float4*)fk;
        #pragma unroll
        for (int u = 0; u < 4; ++u) {
            half4 ks;
            ks[0] = (_Float16)kq[u].x; ks[1] = (_Float16)kq[u].y;
            ks[2] = (_Float16)kq[u].z; ks[3] = (_Float16)kq[u].w;
            *(half4*)&Klds[kb][u * 16 + srow][scol] = ks;
        }
        #pragma unroll
        for (int c = 0; c < 4; ++c) {
            half4 vs;
            vs[0] = (_Float16)fv[4 * c + 0]; vs[1] = (_Float16)fv[4 * c + 1];
            vs[2] = (_Float16)fv[4 * c + 2]; vs[3] = (_Float16)fv[4 * c + 3];
            // kv>>2 = 4*vw + c; pos = (kv>>2 + d + 4*(d>>4)) & 15, d = vlane
            const int pp = ((4 * vw + c) + vlane + 4 * (vlane >> 4)) & 15;
            *(half4*)((char*)&Vtlds[vb][vlane][0] + pp * 8) = vs;
        }
    };

    // ---- per-strip state ----
    const float cs = 0.18033688011112042f; // (1/8) * log2(e), folded into Q
    const int qY_abs = dY * 64 + wrow * 16 + l16;
    const int qX_abs = dX * 64 + wrow * 16 + l16;
    half8 qfY[2], qfX[2];
    auto loadQ = [&](half8* qf, int q_abs) {
        #pragma unroll
        for (int c = 0; c < 2; ++c) {
            const float* pq = Qb + (size_t)q_abs * D_ + c * 32 + quad * 8;
            float4 a = *(const float4*)(pq);
            float4 b = *(const float4*)(pq + 4);
            half8 f;
            f[0] = (_Float16)(a.x * cs); f[1] = (_Float16)(a.y * cs);
            f[2] = (_Float16)(a.z * cs); f[3] = (_Float16)(a.w * cs);
            f[4] = (_Float16)(b.x * cs); f[5] = (_Float16)(b.y * cs);
            f[6] = (_Float16)(b.z * cs); f[7] = (_Float16)(b.w * cs);
            qf[c] = f;
        }
    };
    loadQ(qfY, qY_abs);
    loadQ(qfX, qX_abs);

    f32x4 oY[4], oX[4];
    #pragma unroll
    for (int n = 0; n < 4; ++n) {
        oY[n] = (f32x4){0.f, 0.f, 0.f, 0.f};
        oX[n] = (f32x4){0.f, 0.f, 0.f, 0.f};
    }
    f32x4 lsqY = (f32x4){0.f, 0.f, 0.f, 0.f};   // row sums via ones-MFMA
    f32x4 lsqX = (f32x4){0.f, 0.f, 0.f, 0.f};
    half4 one4;
    one4[0] = (_Float16)1.f; one4[1] = (_Float16)1.f;
    one4[2] = (_Float16)1.f; one4[3] = (_Float16)1.f;

    // P fragments held ACROSS iterations (pipeline stage boundary).
    half4 phX[4], phY[4];

    // ---- pipeline prologue (dX >= 16: tiles 0,1 always exist) ----
    prefetch(0);
    stage(0);
    prefetch(BN);
    BARRIER();

    // ---- main loop ----
    for (int t = 0; t <= dX; ++t) {
        const int kb = t & 1;

        if (t < dX)      stage(t + 1);           // regs prefetched last iter
        if (t + 2 <= dX) prefetch((t + 2) * BN);

        const int  kv0     = t * BN;
        const bool bothNow = (t <= dY);          // block-uniform

        // ---- chain 1: QK^T(t) ----
        f32x4 sX[4], sY[4];
        #pragma unroll
        for (int n = 0; n < 4; ++n) {
            f32x4 aX = (f32x4){0.f, 0.f, 0.f, 0.f};
            f32x4 aY = (f32x4){0.f, 0.f, 0.f, 0.f};
            #pragma unroll
            for (int c = 0; c < 2; ++c) {
                half8 kf = *(const half8*)&Klds[kb][n * 16 + l16][c * 32 + quad * 8];
                aX = __builtin_amdgcn_mfma_f32_16x16x32_f16(kf, qfX[c], aX, 0, 0, 0);
                if (bothNow)
                    aY = __builtin_amdgcn_mfma_f32_16x16x32_f16(kf, qfY[c], aY, 0, 0, 0);
            }
            sX[n] = aX; sY[n] = aY;
        }
        if (bothNow && t == dY) {                // short-strip diagonal mask
            #pragma unroll
            for (int n = 0; n < 4; ++n) {
                const int kvr = kv0 + n * 16 + quad * 4;
                #pragma unroll
                for (int r = 0; r < 4; ++r)
                    if (kvr + r > qY_abs) sY[n][r] = -1e30f;
            }
        }
        if (t == dX) {                           // long-strip diagonal mask
            #pragma unroll
            for (int n = 0; n < 4; ++n) {
                const int kvr = kv0 + n * 16 + quad * 4;
                #pragma unroll
                for (int r = 0; r < 4; ++r)
                    if (kvr + r > qX_abs) sX[n][r] = -1e30f;
            }
        }

        // ---- chain 2: PV(t-1) + lsq(t-1), independent of chain 1 ----
        if (t > 0) {
            const int  vb       = (t - 1) % 3;
            const bool prevBoth = (t - 1 <= dY);
            #pragma unroll
            for (int nk = 0; nk < 4; ++nk) {
                lsqX = __builtin_amdgcn_mfma_f32_16x16x16f16(phX[nk], one4, lsqX, 0, 0, 0);
                if (prevBoth)
                    lsqY = __builtin_amdgcn_mfma_f32_16x16x16f16(phY[nk], one4, lsqY, 0, 0, 0);
            }
            #pragma unroll
            for (int nt = 0; nt < 4; ++nt) {
                const char* row = (const char*)&Vtlds[vb][nt * 16 + l16][0];
                #pragma unroll
                for (int nk = 0; nk < 4; ++nk) {
                    const int pp = (4 * nk + quad + l16 + 4 * nt) & 15;
                    half4 bv = *(const half4*)(row + pp * 8);
                    oX[nt] = __builtin_amdgcn_mfma_f32_16x16x16f16(phX[nk], bv, oX[nt], 0, 0, 0);
                    if (prevBoth)
                        oY[nt] = __builtin_amdgcn_mfma_f32_16x16x16f16(phY[nk], bv, oY[nt], 0, 0, 0);
                }
            }
        }

        // ---- exp(t) -> ph (consumed next iteration) ----
        #pragma unroll
        for (int n = 0; n < 4; ++n)
            #pragma unroll
            for (int r = 0; r < 4; ++r) {
                phX[n][r] = (_Float16)__builtin_amdgcn_exp2f(sX[n][r]);
                if (bothNow)
                    phY[n][r] = (_Float16)__builtin_amdgcn_exp2f(sY[n][r]);
            }

        if (t < dX) BARRIER();
    }

    // ---- drain: PV(dX) + lsq(dX), long strip only ----
    {
        const int vb = dX % 3;
        #pragma unroll
        for (int nk = 0; nk < 4; ++nk)
            lsqX = __builtin_amdgcn_mfma_f32_16x16x16f16(phX[nk], one4, lsqX, 0, 0, 0);
        #pragma unroll
        for (int nt = 0; nt < 4; ++nt) {
            const char* row = (const char*)&Vtlds[vb][nt * 16 + l16][0];
            #pragma unroll
            for (int nk = 0; nk < 4; ++nk) {
                const int pp = (4 * nk + quad + l16 + 4 * nt) & 15;
                half4 bv = *(const half4*)(row + pp * 8);
                oX[nt] = __builtin_amdgcn_mfma_f32_16x16x16f16(phX[nk], bv, oX[nt], 0, 0, 0);
            }
        }
    }

    // ---- epilogue (wave-private): normalize by MFMA row-sums, store ----
    // lsq[r] holds the full row sum for q = quad*4 + r (identical in all l16).
    auto epi = [&](const f32x4* o, f32x4 lsq, int d) {
        float linv[4];
        #pragma unroll
        for (int r = 0; r < 4; ++r) linv[r] = 1.0f / lsq[r];
        const int qr0 = d * 64 + wrow * 16 + quad * 4;
        #pragma unroll
        for (int nt = 0; nt < 4; ++nt)
            #pragma unroll
            for (int r = 0; r < 4; ++r)
                Ob[(size_t)(qr0 + r) * D_ + nt * 16 + l16] = o[nt][r] * linv[r];
    };
    epi(oY, lsqY, dY);
    epi(oX, lsqX, dX);
}

extern "C" void kernel_launch(void* const* d_in, const int* in_sizes, int n_in,
                              void* d_out, int out_size, void* d_ws, size_t ws_size,
                              hipStream_t stream) {
    const float* Q = (const float*)d_in[0];
    const float* K = (const float*)d_in[1];
    const float* V = (const float*)d_in[2];
    float*       O = (float*)d_out;
    fa_fwd<<<dim3(16 * B_ * H_), dim3(256), 0, stream>>>(Q, K, V, O);
}

// Round 8
// 120.678 us; speedup vs baseline: 1.2082x; 1.1768x over previous
//
#include <hip/hip_runtime.h>
#include <stdint.h>

// B=2, H=16, L=2048, D=64 causal attention, fp32 in/out.
#define B_ 2
#define H_ 16
#define L_ 2048
#define D_ 64
#define BN 64   // KV rows per tile; also q rows per strip

typedef __attribute__((ext_vector_type(8))) _Float16 half8;
typedef __attribute__((ext_vector_type(4))) _Float16 half4;
typedef __attribute__((ext_vector_type(4))) float    f32x4;

// ROUND-8: r5 skeleton (proven best, 54.1us: 256-thr block owns strip pair
// (p,31-p), all 4 waves compute both strips per tile sharing K/V LDS reads,
// stage+prefetch at top, __syncthreads at bottom) with ONE structural change:
// TWO kv-tiles per barrier period.
//
// WHY: pipe audit of r5 shows every pipe <=35% busy (LDS 930cyc/2650, VALU
// 28%, MFMA 21%) yet per-unit time is flat (~2000cyc) across 1/2/4 waves per
// SIMD (r6/r5/r1) -> stalls are SYNCHRONIZED: between barriers each wave has
// exactly one dependency chain (ds_read -> QK^T -> exp2 -> cvt -> PV), all
// waves stall at the same chain points, and the barrier resyncs them.
// Fix: put TWO complete independent per-tile chains in each barrier-to-
// barrier region (straight-line code, no cross-barrier state, no
// sched_barrier pins — the r7 mistakes). Compiler interleaves the chains;
// barrier count also halves.
//
// LDS: 2 periods x 2 tiles (69,632 B -> 2 blocks/CU, same as r4's footprint).
// Hazards (classic, __syncthreads drains vmcnt+lgkmcnt): stage(per^1) at
// period u overwrites buffers last read at period u-1, fenced by u-1's
// barrier; prefetch regs written at u are consumed by stage at u+1.
//
// Kept: cs=(1/8)log2e folded into fp16 Q; row sums via ones-MFMA; no
// rotation (r5: null perf, +25% FETCH). New: float4 V prefetch (4 dwordx4
// instead of 16 dword); s_setprio(1) around MFMA clusters (T5).
//
// __launch_bounds__ 2nd arg is MIN BLOCKS PER CU on this hipcc (r3
// post-mortem: (512,4) capped VGPR at 64 -> spill catastrophe).
//
// blockIdx decode (assumes round-robin i%8 -> XCD): bh = ((i>>3)&3)*8+(i&7)
// gives each XCD all 16 pairs of 4 fixed bh's -> K/V stream L2-local.

__global__ __launch_bounds__(256, 2) void fa_fwd(
    const float* __restrict__ Q, const float* __restrict__ K,
    const float* __restrict__ V, float* __restrict__ O)
{
    const int i  = blockIdx.x;
    const int bh = ((i >> 3) & 3) * 8 + (i & 7);
    const int p  = i >> 5;               // 0..15
    const int dY = p;                    // short strip diagonal
    const int dX = 31 - p;               // long strip diagonal (>= 16)

    const int tid  = threadIdx.x;
    const int wrow = tid >> 6;           // wave = 16-row band within each strip
    const int lane = tid & 63;
    const int l16  = lane & 15;
    const int quad = lane >> 4;

    const size_t base = (size_t)bh * (size_t)(L_ * D_);
    const float* Qb = Q + base;
    const float* Kb = K + base;
    const float* Vb = V + base;
    float*       Ob = O + base;

    // 2 periods x 2 tiles each (69,632 B total).
    __shared__ __align__(16) _Float16 Klds [2][2][BN][72];  // row-major K
    __shared__ __align__(16) _Float16 Vtlds[2][2][D_][64];  // V^T, 8B-swizzled

    // ---- staging thread mapping ----
    const int srow  = tid >> 4;          // K: row 0..15 (x4)
    const int scol  = (tid & 15) * 4;    // K: col
    const int dgrp  = lane & 15;         // V: d-group (4 d's)
    const int kvq   = lane >> 4;
    const int kvblk = wrow * 4 + kvq;    // V: kv-block 0..15 (4 kv's)

    float4 fk4[2][4];  // K prefetch regs, per tile-slot
    float4 fv4[2][4];  // V prefetch regs (4 d x 4 kv), per tile-slot

    auto prefetchTile = [&](int s, int t) {
        const int kv0 = t * BN;
        const float* kp = Kb + (size_t)kv0 * D_ + (size_t)tid * 4;
        #pragma unroll
        for (int u = 0; u < 4; ++u) fk4[s][u] = *(const float4*)(kp + u * 1024);
        const float* vp = Vb + (size_t)(kv0 + kvblk * 4) * D_ + dgrp * 4;
        #pragma unroll
        for (int rr = 0; rr < 4; ++rr) fv4[s][rr] = *(const float4*)(vp + rr * D_);
    };

    auto stageTile = [&](int per, int s) {
        #pragma unroll
        for (int u = 0; u < 4; ++u) {
            half4 ks;
            ks[0] = (_Float16)fk4[s][u].x; ks[1] = (_Float16)fk4[s][u].y;
            ks[2] = (_Float16)fk4[s][u].z; ks[3] = (_Float16)fk4[s][u].w;
            *(half4*)&Klds[per][s][u * 16 + srow][scol] = ks;
        }
        #pragma unroll
        for (int dd = 0; dd < 4; ++dd) {
            const int d = dgrp * 4 + dd;
            half4 vs;
            vs[0] = (_Float16)((&fv4[s][0].x)[dd]);
            vs[1] = (_Float16)((&fv4[s][1].x)[dd]);
            vs[2] = (_Float16)((&fv4[s][2].x)[dd]);
            vs[3] = (_Float16)((&fv4[s][3].x)[dd]);
            // same swizzle as before: pp = (kvblk + d + 4*(d>>4)) & 15
            const int pp = (kvblk + d + 4 * (d >> 4)) & 15;
            *(half4*)((char*)&Vtlds[per][s][d][0] + pp * 8) = vs;
        }
    };

    // ---- per-strip state ----
    const float cs = 0.18033688011112042f; // (1/8) * log2(e), folded into Q
    const int qY_abs = dY * 64 + wrow * 16 + l16;
    const int qX_abs = dX * 64 + wrow * 16 + l16;
    half8 qfY[2], qfX[2];
    auto loadQ = [&](half8* qf, int q_abs) {
        #pragma unroll
        for (int c = 0; c < 2; ++c) {
            const float* pq = Qb + (size_t)q_abs * D_ + c * 32 + quad * 8;
            float4 a = *(const float4*)(pq);
            float4 b = *(const float4*)(pq + 4);
            half8 f;
            f[0] = (_Float16)(a.x * cs); f[1] = (_Float16)(a.y * cs);
            f[2] = (_Float16)(a.z * cs); f[3] = (_Float16)(a.w * cs);
            f[4] = (_Float16)(b.x * cs); f[5] = (_Float16)(b.y * cs);
            f[6] = (_Float16)(b.z * cs); f[7] = (_Float16)(b.w * cs);
            qf[c] = f;
        }
    };
    loadQ(qfY, qY_abs);
    loadQ(qfX, qX_abs);

    f32x4 oY[4], oX[4];
    #pragma unroll
    for (int n = 0; n < 4; ++n) {
        oY[n] = (f32x4){0.f, 0.f, 0.f, 0.f};
        oX[n] = (f32x4){0.f, 0.f, 0.f, 0.f};
    }
    f32x4 lsqY = (f32x4){0.f, 0.f, 0.f, 0.f};   // row sums via ones-MFMA
    f32x4 lsqX = (f32x4){0.f, 0.f, 0.f, 0.f};
    half4 one4;
    one4[0] = (_Float16)1.f; one4[1] = (_Float16)1.f;
    one4[2] = (_Float16)1.f; one4[3] = (_Float16)1.f;

    // ---- one tile of compute (r5 body, parameterized by buffer) ----
    auto doTile = [&](int per, int s, int t) {
        const int kv0 = t * BN;
        if (t <= dY) {
            // ---- both strips, shared K/V LDS reads ----
            f32x4 sX[4], sY[4];
            __builtin_amdgcn_s_setprio(1);
            #pragma unroll
            for (int n = 0; n < 4; ++n) {
                f32x4 aX = (f32x4){0.f, 0.f, 0.f, 0.f};
                f32x4 aY = (f32x4){0.f, 0.f, 0.f, 0.f};
                #pragma unroll
                for (int c = 0; c < 2; ++c) {
                    half8 kf = *(const half8*)&Klds[per][s][n * 16 + l16][c * 32 + quad * 8];
                    aX = __builtin_amdgcn_mfma_f32_16x16x32_f16(kf, qfX[c], aX, 0, 0, 0);
                    aY = __builtin_amdgcn_mfma_f32_16x16x32_f16(kf, qfY[c], aY, 0, 0, 0);
                }
                sX[n] = aX; sY[n] = aY;
            }
            __builtin_amdgcn_s_setprio(0);
            if (t == dY) {                       // short-strip diagonal mask
                #pragma unroll
                for (int n = 0; n < 4; ++n) {
                    const int kvr = kv0 + n * 16 + quad * 4;
                    #pragma unroll
                    for (int r = 0; r < 4; ++r)
                        if (kvr + r > qY_abs) sY[n][r] = -1e30f;
                }
            }
            half4 phX[4], phY[4];
            #pragma unroll
            for (int n = 0; n < 4; ++n)
                #pragma unroll
                for (int r = 0; r < 4; ++r) {
                    phX[n][r] = (_Float16)__builtin_amdgcn_exp2f(sX[n][r]);
                    phY[n][r] = (_Float16)__builtin_amdgcn_exp2f(sY[n][r]);
                }
            __builtin_amdgcn_s_setprio(1);
            #pragma unroll
            for (int nk = 0; nk < 4; ++nk) {
                lsqX = __builtin_amdgcn_mfma_f32_16x16x16f16(phX[nk], one4, lsqX, 0, 0, 0);
                lsqY = __builtin_amdgcn_mfma_f32_16x16x16f16(phY[nk], one4, lsqY, 0, 0, 0);
            }
            #pragma unroll
            for (int nt = 0; nt < 4; ++nt) {
                const char* row = (const char*)&Vtlds[per][s][nt * 16 + l16][0];
                #pragma unroll
                for (int nk = 0; nk < 4; ++nk) {
                    const int pp = (4 * nk + quad + l16 + 4 * nt) & 15;
                    half4 bv = *(const half4*)(row + pp * 8);
                    oX[nt] = __builtin_amdgcn_mfma_f32_16x16x16f16(phX[nk], bv, oX[nt], 0, 0, 0);
                    oY[nt] = __builtin_amdgcn_mfma_f32_16x16x16f16(phY[nk], bv, oY[nt], 0, 0, 0);
                }
            }
            __builtin_amdgcn_s_setprio(0);
        } else {
            // ---- long strip only ----
            f32x4 sX[4];
            __builtin_amdgcn_s_setprio(1);
            #pragma unroll
            for (int n = 0; n < 4; ++n) {
                f32x4 aX = (f32x4){0.f, 0.f, 0.f, 0.f};
                #pragma unroll
                for (int c = 0; c < 2; ++c) {
                    half8 kf = *(const half8*)&Klds[per][s][n * 16 + l16][c * 32 + quad * 8];
                    aX = __builtin_amdgcn_mfma_f32_16x16x32_f16(kf, qfX[c], aX, 0, 0, 0);
                }
                sX[n] = aX;
            }
            __builtin_amdgcn_s_setprio(0);
            if (t == dX) {                       // long-strip diagonal mask
                #pragma unroll
                for (int n = 0; n < 4; ++n) {
                    const int kvr = kv0 + n * 16 + quad * 4;
                    #pragma unroll
                    for (int r = 0; r < 4; ++r)
                        if (kvr + r > qX_abs) sX[n][r] = -1e30f;
                }
            }
            half4 phX[4];
            #pragma unroll
            for (int n = 0; n < 4; ++n)
                #pragma unroll
                for (int r = 0; r < 4; ++r)
                    phX[n][r] = (_Float16)__builtin_amdgcn_exp2f(sX[n][r]);
            __builtin_amdgcn_s_setprio(1);
            #pragma unroll
            for (int nk = 0; nk < 4; ++nk)
                lsqX = __builtin_amdgcn_mfma_f32_16x16x16f16(phX[nk], one4, lsqX, 0, 0, 0);
            #pragma unroll
            for (int nt = 0; nt < 4; ++nt) {
                const char* row = (const char*)&Vtlds[per][s][nt * 16 + l16][0];
                #pragma unroll
                for (int nk = 0; nk < 4; ++nk) {
                    const int pp = (4 * nk + quad + l16 + 4 * nt) & 15;
                    half4 bv = *(const half4*)(row + pp * 8);
                    oX[nt] = __builtin_amdgcn_mfma_f32_16x16x16f16(phX[nk], bv, oX[nt], 0, 0, 0);
                }
            }
            __builtin_amdgcn_s_setprio(0);
        }
    };

    // ---- prologue: stage period 0 (tiles 0,1), prefetch period 1 (2,3) ----
    // dX >= 16, so tiles 0..3 always exist.
    prefetchTile(0, 0);
    prefetchTile(1, 1);
    stageTile(0, 0);
    stageTile(0, 1);
    prefetchTile(0, 2);
    prefetchTile(1, 3);
    __syncthreads();

    // ---- main loop: one barrier per TWO tiles ----
    const int uMax = (dX + 2) >> 1;              // ceil((dX+1)/2)
    for (int u = 0; u < uMax; ++u) {
        const int per = u & 1;

        if (u + 1 < uMax) {
            stageTile(per ^ 1, 0);               // tile 2u+2 (exists: <= dX)
            if (2 * u + 3 <= dX) stageTile(per ^ 1, 1);
            if (2 * u + 4 <= dX) prefetchTile(0, 2 * u + 4);
            if (2 * u + 5 <= dX) prefetchTile(1, 2 * u + 5);
        }

        doTile(per, 0, 2 * u);                   // 2u <= dX by uMax def
        if (2 * u + 1 <= dX) doTile(per, 1, 2 * u + 1);

        if (u + 1 < uMax) __syncthreads();
    }

    // ---- epilogue (wave-private): normalize by MFMA row-sums, store ----
    // lsq[r] holds the full row sum for q = quad*4 + r (identical in all l16).
    auto epi = [&](const f32x4* o, f32x4 lsq, int d) {
        float linv[4];
        #pragma unroll
        for (int r = 0; r < 4; ++r) linv[r] = 1.0f / lsq[r];
        const int qr0 = d * 64 + wrow * 16 + quad * 4;
        #pragma unroll
        for (int nt = 0; nt < 4; ++nt)
            #pragma unroll
            for (int r = 0; r < 4; ++r)
                Ob[(size_t)(qr0 + r) * D_ + nt * 16 + l16] = o[nt][r] * linv[r];
    };
    epi(oY, lsqY, dY);
    epi(oX, lsqX, dX);
}

extern "C" void kernel_launch(void* const* d_in, const int* in_sizes, int n_in,
                              void* d_out, int out_size, void* d_ws, size_t ws_size,
                              hipStream_t stream) {
    const float* Q = (const float*)d_in[0];
    const float* K = (const float*)d_in[1];
    const float* V = (const float*)d_in[2];
    float*       O = (float*)d_out;
    fa_fwd<<<dim3(16 * B_ * H_), dim3(256), 0, stream>>>(Q, K, V, O);
}